// Round 12
// baseline (346.577 us; speedup 1.0000x reference)
//
#include <hip/hip_runtime.h>

#define NN 50000
#define FDIM 256
#define HDIM 256
#define BN_EPS 1e-5f
#define RB 32     // rows per fallback GEMM block
#define KC 16
#define NP 264    // padded LDS row stride (bf16 elems)
#define SCAN_CHUNK 1024
#define NBLK_SCAN ((NN + SCAN_CHUNK - 1) / SCAN_CHUNK)

// partition params
#define BKT 32                 // nodes per bucket == fused GEMM tile rows
#define NBKT 1563              // ceil(NN/32)
#define NBH 782                // buckets in half A (half B = 781)
#define ECAP 1280              // LDS pair capacity in agg (mean 1024, ~8 sigma)
#define CAP 1280               // fixed slot capacity per bucket (== ECAP)
#define SBUF2 3200             // per-fill-block sorted chunk capacity
#define NFB_MIN 512            // fill blocks per half
#define SMEM_INTS 6144         // 24576 B shared union (agg needs 6082, fill 5056)
// pair encoding: [bkt_local:11][src:16][ldst:5]
#define PAIR_SRC(p) (((p) >> 5) & 0xFFFFu)
#define PAIR_LDST(p) ((p) & 31u)

typedef __attribute__((ext_vector_type(8))) short short8v;
typedef __attribute__((ext_vector_type(8))) unsigned short ushort8v;
typedef __attribute__((ext_vector_type(4))) float f32x4;

__device__ __forceinline__ float b2f(unsigned short u) {
    return __uint_as_float(((unsigned)u) << 16);
}
__device__ __forceinline__ unsigned short f2b(float f) {  // RNE
    unsigned u = __float_as_uint(f);
    return (unsigned short)((u + 0x7FFFu + ((u >> 16) & 1u)) >> 16);
}

// ---------- fill for a bucket range [bkt_lo,bkt_hi) (r0/r7-verified structure,
//            + dst-range predicate; 256 threads; carved LDS) ----------
__device__ __forceinline__ void fill_range(int cid, int nfb, int* smem,
                                           const int* __restrict__ src,
                                           const int* __restrict__ dst,
                                           int* __restrict__ bcnt,
                                           unsigned int* __restrict__ pairs,
                                           int E, int bkt_lo, int bkt_hi) {
    int* lhist = smem;              // [<=800] counts -> cursor -> delta
    int* lofs  = smem + 800;        // [<=800] local exclusive offsets
    int* ts    = smem + 1600;       // [256]
    unsigned int* sbuf = (unsigned int*)(smem + 1856);  // [3200]
    const int t = threadIdx.x;
    const int nbh = bkt_hi - bkt_lo;
    const int chunk = (E + nfb - 1) / nfb;
    const int c0 = cid * chunk;
    const int c1 = min(E, c0 + chunk);

    for (int i = t; i < nbh; i += 256) lhist[i] = 0;
    __syncthreads();
    for (int e = c0 + t; e < c1; e += 256) {
        int b = dst[e] >> 5;
        if (b >= bkt_lo && b < bkt_hi) atomicAdd(&lhist[b - bkt_lo], 1);
    }
    __syncthreads();
    int ntot;
    {
        int i0 = t * 4;             // 4*256 = 1024 >= nbh
        int s = 0;
        int loc[4];
        for (int i = 0; i < 4; i++) {
            int idx = i0 + i;
            loc[i] = (idx < nbh) ? lhist[idx] : 0;
            s += loc[i];
        }
        ts[t] = s;
        __syncthreads();
        for (int off = 1; off < 256; off <<= 1) {
            int val = (t >= off) ? ts[t - off] : 0;
            __syncthreads();
            ts[t] += val;
            __syncthreads();
        }
        int run = ts[t] - s;
        for (int i = 0; i < 4; i++) {
            int idx = i0 + i;
            if (idx < nbh) {
                lofs[idx] = run;
                run += loc[i];
            }
        }
        ntot = ts[255];             // total kept edges in this chunk
    }
    __syncthreads();
    for (int i = t; i < nbh; i += 256) lhist[i] = lofs[i];
    __syncthreads();
    // place kept edges into sorted LDS buffer (kept <= chunk <= SBUF2 always)
    for (int e = c0 + t; e < c1; e += 256) {
        int d = dst[e];
        int b = d >> 5;
        if (b >= bkt_lo && b < bkt_hi) {
            unsigned bl = (unsigned)(b - bkt_lo);
            int rank = atomicAdd(&lhist[bl], 1);
            sbuf[rank] = (bl << 21) | ((unsigned)src[e] << 5) | ((unsigned)d & 31u);
        }
    }
    __syncthreads();
    // reserve slot runs; lhist becomes delta = (bkt_global*CAP + old) - lofs
    for (int i = t; i < nbh; i += 256) {
        int cnt = lhist[i] - lofs[i];
        int gb = cnt ? ((bkt_lo + i) * CAP + atomicAdd(&bcnt[bkt_lo + i], cnt)) : 0;
        lhist[i] = gb - lofs[i];
    }
    __syncthreads();
    // coalesced write-out, guarded against slot overflow
    for (int j = t; j < ntot; j += 256) {
        unsigned int p = sbuf[j];
        unsigned bl = p >> 21;
        int pos = j + lhist[bl];
        if (pos < (int)((bkt_lo + bl + 1) * CAP)) pairs[pos] = p;
    }
}

// ---------- agg+GEMM+BN for one bucket (r7-verified body; carved LDS) ----------
__device__ __forceinline__ void agg_bucket(int bkt, int* smem,
                                           const ushort4* __restrict__ xb4,
                                           const unsigned int* __restrict__ pairs,
                                           const int* __restrict__ bcnt,
                                           const int* __restrict__ srcv,
                                           const int* __restrict__ dstv, int E,
                                           const unsigned short* __restrict__ Wb,
                                           const float* __restrict__ bias,
                                           unsigned short* __restrict__ hb,
                                           float* __restrict__ stat) {
    unsigned int* lp = (unsigned int*)smem;          // [1280]
    int* lhist = smem + 1280;                        // [32]
    int* lofs  = smem + 1312;                        // [33]
    unsigned short* As = (unsigned short*)(smem + 1346);  // [32*264] = 4224 ints
    float* ssum = (float*)(smem + 5570);             // [256]
    float* ssq  = (float*)(smem + 5826);             // [256]
    const int t = threadIdx.x;
    const int lane = t & 63;
    const int wid = t >> 6;
    const int q = lane >> 4;
    const int l16 = lane & 15;
    const int v0 = bkt * BKT;
    const int ebeg = bkt * CAP;
    const int ecnt = bcnt[bkt];
    const int vrows = min(BKT, NN - v0);

    ssum[t] = 0.f;
    ssq[t] = 0.f;

    if (ecnt <= ECAP) {
        if (t < BKT) lhist[t] = 0;
        __syncthreads();
        for (int e = t; e < ecnt; e += 256)
            atomicAdd(&lhist[PAIR_LDST(pairs[ebeg + e])], 1);
        __syncthreads();
        if (t == 0) {
            int run = 0;
            for (int r = 0; r < BKT; r++) { lofs[r] = run; run += lhist[r]; }
            lofs[BKT] = run;
        }
        __syncthreads();
        if (t < BKT) lhist[t] = lofs[t];
        __syncthreads();
        for (int e = t; e < ecnt; e += 256) {
            unsigned int p = pairs[ebeg + e];
            int pos = atomicAdd(&lhist[PAIR_LDST(p)], 1);
            lp[pos] = p;
        }
        __syncthreads();
        // gather: wave wid owns rows wid*8 .. wid*8+7
#pragma unroll
        for (int i = 0; i < 8; i++) {
            int r = wid * 8 + i;
            int v = v0 + r;
            if (v < NN) {
                ushort4 u0 = xb4[(size_t)v * 64 + lane];
                float a0 = b2f(u0.x), a1 = b2f(u0.y), a2 = b2f(u0.z), a3 = b2f(u0.w);
                int e0 = __builtin_amdgcn_readfirstlane(lofs[r]);
                int e1 = __builtin_amdgcn_readfirstlane(lofs[r + 1]);
                int e = e0;
                for (; e + 16 <= e1; e += 16) {
                    ushort4 u[16];
#pragma unroll
                    for (int j = 0; j < 16; j++)
                        u[j] = xb4[(size_t)PAIR_SRC(lp[e + j]) * 64 + lane];
#pragma unroll
                    for (int j = 0; j < 16; j++) {
                        a0 += b2f(u[j].x); a1 += b2f(u[j].y);
                        a2 += b2f(u[j].z); a3 += b2f(u[j].w);
                    }
                }
                for (; e + 4 <= e1; e += 4) {
                    ushort4 ua = xb4[(size_t)PAIR_SRC(lp[e]) * 64 + lane];
                    ushort4 ub = xb4[(size_t)PAIR_SRC(lp[e + 1]) * 64 + lane];
                    ushort4 uc = xb4[(size_t)PAIR_SRC(lp[e + 2]) * 64 + lane];
                    ushort4 ud = xb4[(size_t)PAIR_SRC(lp[e + 3]) * 64 + lane];
                    a0 += (b2f(ua.x) + b2f(ub.x)) + (b2f(uc.x) + b2f(ud.x));
                    a1 += (b2f(ua.y) + b2f(ub.y)) + (b2f(uc.y) + b2f(ud.y));
                    a2 += (b2f(ua.z) + b2f(ub.z)) + (b2f(uc.z) + b2f(ud.z));
                    a3 += (b2f(ua.w) + b2f(ub.w)) + (b2f(uc.w) + b2f(ud.w));
                }
                for (; e < e1; e++) {
                    ushort4 ua = xb4[(size_t)PAIR_SRC(lp[e]) * 64 + lane];
                    a0 += b2f(ua.x); a1 += b2f(ua.y); a2 += b2f(ua.z); a3 += b2f(ua.w);
                }
                *(ushort4*)(As + r * NP + lane * 4) =
                    make_ushort4(f2b(a0), f2b(a1), f2b(a2), f2b(a3));
            } else {
                *(ushort4*)(As + r * NP + lane * 4) = make_ushort4(0, 0, 0, 0);
            }
        }
    } else {
        // slot overflow (statistically unreachable): correct raw rescan of edge list
#pragma unroll
        for (int i = 0; i < 8; i++) {
            int r = wid * 8 + i;
            int v = v0 + r;
            float a0 = 0.f, a1 = 0.f, a2 = 0.f, a3 = 0.f;
            if (v < NN) {
                ushort4 u0 = xb4[(size_t)v * 64 + lane];
                a0 = b2f(u0.x); a1 = b2f(u0.y); a2 = b2f(u0.z); a3 = b2f(u0.w);
                for (int e = 0; e < E; e++) {
                    if (dstv[e] == v) {
                        ushort4 cu = xb4[(size_t)srcv[e] * 64 + lane];
                        a0 += b2f(cu.x); a1 += b2f(cu.y); a2 += b2f(cu.z); a3 += b2f(cu.w);
                    }
                }
            }
            *(ushort4*)(As + r * NP + lane * 4) =
                make_ushort4(f2b(a0), f2b(a1), f2b(a2), f2b(a3));
        }
    }
    __syncthreads();

    // ---- MFMA GEMM on the 32xFDIM A-tile ----
    f32x4 acc[2][4];
#pragma unroll
    for (int mt = 0; mt < 2; mt++)
#pragma unroll
        for (int nt = 0; nt < 4; nt++) acc[mt][nt] = (f32x4)0.f;

    const int w = wid;
#pragma unroll
    for (int ks = 0; ks < 8; ks++) {
        const int kk = ks * 32;
        short8v af[2], bf_[4];
#pragma unroll
        for (int mt = 0; mt < 2; mt++)
            af[mt] = *(const short8v*)(As + (mt * 16 + l16) * NP + kk + q * 8);
#pragma unroll
        for (int nt = 0; nt < 4; nt++)
            bf_[nt] = *(const short8v*)(Wb + (size_t)(w * 64 + nt * 16 + l16) * FDIM + kk + q * 8);
#pragma unroll
        for (int mt = 0; mt < 2; mt++)
#pragma unroll
            for (int nt = 0; nt < 4; nt++)
                acc[mt][nt] = __builtin_amdgcn_mfma_f32_16x16x32_bf16(af[mt], bf_[nt], acc[mt][nt], 0, 0, 0);
    }

    // epilogue: bias, bf16 store, BN stats
#pragma unroll
    for (int nt = 0; nt < 4; nt++) {
        const int col = w * 64 + nt * 16 + l16;
        const float bcol = bias[col];
        float s = 0.f, qq = 0.f;
#pragma unroll
        for (int mt = 0; mt < 2; mt++) {
            const int rbase = mt * 16 + q * 4;
#pragma unroll
            for (int r = 0; r < 4; r++) {
                int row = rbase + r;
                if (row < vrows) {
                    float v = acc[mt][nt][r] + bcol;
                    hb[(size_t)(v0 + row) * FDIM + col] = f2b(v);
                    s += v;
                    qq += v * v;
                }
            }
        }
        atomicAdd(&ssum[col], s);
        atomicAdd(&ssq[col], qq);
    }
    __syncthreads();
    atomicAdd(&stat[t], ssum[t]);
    atomicAdd(&stat[256 + t], ssq[t]);
}

// ====== stage 1: fillA (buckets [0,NBH)) + fp32->bf16 convert, co-scheduled ======
__launch_bounds__(256, 6)
__global__ void k_cvtfillA(const float4* __restrict__ x, const float4* __restrict__ W,
                           ushort4* __restrict__ xb, ushort4* __restrict__ Wb,
                           int nx4, int nw4,
                           const int* __restrict__ src, const int* __restrict__ dst,
                           int* __restrict__ bcnt, unsigned int* __restrict__ pairs,
                           int E, int nfb) {
    __shared__ int smem[SMEM_INTS];
    const int bid = blockIdx.x;
    if (bid < nfb) {
        fill_range(bid, nfb, smem, src, dst, bcnt, pairs, E, 0, NBH);
        return;
    }
    int i = (bid - nfb) * 256 + threadIdx.x;
    if (i < nx4) {
        float4 v = x[i];
        xb[i] = make_ushort4(f2b(v.x), f2b(v.y), f2b(v.z), f2b(v.w));
    } else {
        int j = i - nx4;
        if (j < nw4) {
            float4 v = W[j];
            Wb[j] = make_ushort4(f2b(v.x), f2b(v.y), f2b(v.z), f2b(v.w));
        }
    }
}

// ====== stage 2: fillB (buckets [NBH,NBKT)) co-scheduled with aggA (buckets [0,NBH)) ======
// fillB writes pairs/bcnt for half B only; aggA reads half A only -> disjoint, race-free.
// fill blocks dispatch first (critical path for stage 3).
__launch_bounds__(256, 6)
__global__ void k_mix(const ushort4* __restrict__ xb4, const unsigned int* __restrict__ pairs,
                      int* __restrict__ bcnt,
                      const int* __restrict__ src, const int* __restrict__ dst, int E,
                      const unsigned short* __restrict__ Wb, const float* __restrict__ bias,
                      unsigned short* __restrict__ hb, float* __restrict__ stat, int nfb) {
    __shared__ int smem[SMEM_INTS];
    const int bid = blockIdx.x;
    if (bid < nfb) {
        fill_range(bid, nfb, smem, src, dst, bcnt, (unsigned int*)pairs, E, NBH, NBKT);
        return;
    }
    agg_bucket(bid - nfb, smem, xb4, pairs, bcnt, src, dst, E, Wb, bias, hb, stat);
}

// ====== stage 3: aggB (buckets [NBH,NBKT)) ======
__launch_bounds__(256, 6)
__global__ void k_aggB(const ushort4* __restrict__ xb4, const unsigned int* __restrict__ pairs,
                       const int* __restrict__ bcnt,
                       const int* __restrict__ src, const int* __restrict__ dst, int E,
                       const unsigned short* __restrict__ Wb, const float* __restrict__ bias,
                       unsigned short* __restrict__ hb, float* __restrict__ stat) {
    __shared__ int smem[SMEM_INTS];
    agg_bucket(NBH + blockIdx.x, smem, xb4, pairs, bcnt, src, dst, E, Wb, bias, hb, stat);
}

// ================= BN finalize folded into normalize =================
__global__ void k_norm8f(const ushort8v* __restrict__ hb8, const float* __restrict__ stat,
                         const float* __restrict__ bn_w, const float* __restrict__ bn_b,
                         float4* __restrict__ out, int n8) {
    __shared__ float ss[512];
    const int t = threadIdx.x;
    {
        const float inv_n = 1.0f / (float)NN;
        float mean = stat[t] * inv_n;
        float var = stat[256 + t] * inv_n - mean * mean;
        float sc = bn_w[t] * rsqrtf(var + BN_EPS);
        ss[t] = sc;
        ss[256 + t] = bn_b[t] - mean * sc;
    }
    __syncthreads();
    int i = blockIdx.x * 256 + t;
    if (i >= n8) return;
    ushort8v u = hb8[i];
    int c8 = (i & 31) << 3;
    float4 sc0 = *(const float4*)(ss + c8);
    float4 sc1 = *(const float4*)(ss + c8 + 4);
    float4 sh0 = *(const float4*)(ss + 256 + c8);
    float4 sh1 = *(const float4*)(ss + 256 + c8 + 4);
    float4 v0, v1;
    v0.x = fmaf(b2f(u[0]), sc0.x, sh0.x);
    v0.y = fmaf(b2f(u[1]), sc0.y, sh0.y);
    v0.z = fmaf(b2f(u[2]), sc0.z, sh0.z);
    v0.w = fmaf(b2f(u[3]), sc0.w, sh0.w);
    v1.x = fmaf(b2f(u[4]), sc1.x, sh1.x);
    v1.y = fmaf(b2f(u[5]), sc1.y, sh1.y);
    v1.z = fmaf(b2f(u[6]), sc1.z, sh1.z);
    v1.w = fmaf(b2f(u[7]), sc1.w, sh1.w);
    out[i * 2 + 0] = v0;
    out[i * 2 + 1] = v1;
}

// ================= fallback fp32 path =================
__global__ void k_final(const float* __restrict__ stat, const float* __restrict__ bn_w,
                        const float* __restrict__ bn_b, float* __restrict__ ss) {
    int j = threadIdx.x;
    const float inv_n = 1.0f / (float)NN;
    float mean = stat[j] * inv_n;
    float var = stat[256 + j] * inv_n - mean * mean;
    float sc = bn_w[j] * rsqrtf(var + BN_EPS);
    ss[j] = sc;
    ss[256 + j] = bn_b[j] - mean * sc;
}
__global__ void k_hist(const int* __restrict__ dst, int* __restrict__ cnt, int E) {
    int e = blockIdx.x * blockDim.x + threadIdx.x;
    if (e < E) atomicAdd(&cnt[dst[e]], 1);
}
__global__ void k_scan1(const int* __restrict__ cnt, int* __restrict__ offs,
                        int* __restrict__ bsum) {
    __shared__ int ts[256];
    int t = threadIdx.x;
    int base = blockIdx.x * SCAN_CHUNK + t * 4;
    int v0 = (base + 0 < NN) ? cnt[base + 0] : 0;
    int v1 = (base + 1 < NN) ? cnt[base + 1] : 0;
    int v2 = (base + 2 < NN) ? cnt[base + 2] : 0;
    int v3 = (base + 3 < NN) ? cnt[base + 3] : 0;
    int tsum = v0 + v1 + v2 + v3;
    ts[t] = tsum;
    __syncthreads();
    for (int off = 1; off < 256; off <<= 1) {
        int val = (t >= off) ? ts[t - off] : 0;
        __syncthreads();
        ts[t] += val;
        __syncthreads();
    }
    int excl = ts[t] - tsum;
    if (t == 255) bsum[blockIdx.x] = ts[255];
    if (base + 0 < NN) offs[base + 0] = excl;
    if (base + 1 < NN) offs[base + 1] = excl + v0;
    if (base + 2 < NN) offs[base + 2] = excl + v0 + v1;
    if (base + 3 < NN) offs[base + 3] = excl + v0 + v1 + v2;
}
__global__ void k_scan2(int* __restrict__ bsum, int nb) {
    __shared__ int s[64];
    int t = threadIdx.x;
    s[t] = (t < nb) ? bsum[t] : 0;
    __syncthreads();
    if (t == 0) {
        int run = 0;
        for (int i = 0; i < nb; i++) { int v = s[i]; s[i] = run; run += v; }
    }
    __syncthreads();
    if (t < nb) bsum[t] = s[t];
}
__global__ void k_scan3(int* __restrict__ offs, const int* __restrict__ bsum,
                        int* __restrict__ cursor) {
    int i = blockIdx.x * blockDim.x + threadIdx.x;
    if (i >= NN) return;
    int o = offs[i] + bsum[i >> 10];
    offs[i] = o;
    cursor[i] = o;
}
__global__ void k_bucket(const int* __restrict__ src, const int* __restrict__ dst,
                         int* __restrict__ cursor, int* __restrict__ csr, int E) {
    int e = blockIdx.x * blockDim.x + threadIdx.x;
    if (e >= E) return;
    int pos = atomicAdd(&cursor[dst[e]], 1);
    csr[pos] = src[e];
}
__global__ void k_copy(const float4* __restrict__ x, float4* __restrict__ out, int n4) {
    int i = blockIdx.x * blockDim.x + threadIdx.x;
    if (i < n4) out[i] = x[i];
}
__global__ void k_scatter(const float* __restrict__ x, const int* __restrict__ src,
                          const int* __restrict__ dst, float* __restrict__ out, int E) {
    int t = blockIdx.x * blockDim.x + threadIdx.x;
    int e = t >> 6;
    if (e >= E) return;
    int c = (t & 63) << 2;
    long s = src[e], d = dst[e];
    const float4 v = *(const float4*)(x + s * FDIM + c);
    float* o = out + d * FDIM + c;
    atomicAdd(o + 0, v.x);
    atomicAdd(o + 1, v.y);
    atomicAdd(o + 2, v.z);
    atomicAdd(o + 3, v.w);
}
__launch_bounds__(256)
__global__ void k_gather(const float4* __restrict__ x, const int* __restrict__ offs,
                         const int* __restrict__ cnt, const int* __restrict__ csr,
                         float4* __restrict__ out) {
    int v = blockIdx.x * 4 + (threadIdx.x >> 6);
    if (v >= NN) return;
    int lane = threadIdx.x & 63;
    int beg = __builtin_amdgcn_readfirstlane(offs[v]);
    int d   = __builtin_amdgcn_readfirstlane(cnt[v]);
    float4 acc = x[(size_t)v * 64 + lane];
    int i = 0;
    for (; i + 4 <= d; i += 4) {
        int s0 = csr[beg + i], s1 = csr[beg + i + 1];
        int s2 = csr[beg + i + 2], s3 = csr[beg + i + 3];
        float4 a = x[(size_t)s0 * 64 + lane];
        float4 b = x[(size_t)s1 * 64 + lane];
        float4 c = x[(size_t)s2 * 64 + lane];
        float4 e = x[(size_t)s3 * 64 + lane];
        acc.x += (a.x + b.x) + (c.x + e.x);
        acc.y += (a.y + b.y) + (c.y + e.y);
        acc.z += (a.z + b.z) + (c.z + e.z);
        acc.w += (a.w + b.w) + (c.w + e.w);
    }
    for (; i < d; i++) {
        int s = csr[beg + i];
        float4 a = x[(size_t)s * 64 + lane];
        acc.x += a.x; acc.y += a.y; acc.z += a.z; acc.w += a.w;
    }
    out[(size_t)v * 64 + lane] = acc;
}
__launch_bounds__(256)
__global__ void k_gemm_stats(float* __restrict__ h,
                             const float* __restrict__ W,
                             const float* __restrict__ bias,
                             float* __restrict__ stat) {
    __shared__ float hs[RB * FDIM];
    __shared__ float wt[KC * HDIM];
    const int j = threadIdx.x;
    const int c = j & 63;
    const int g = j >> 6;
    const long row0 = (long)blockIdx.x * RB;
    const int vrows = min(RB, NN - (int)row0);
    const int vf4 = vrows * (FDIM / 4);

    float4* hsv = (float4*)hs;
    const float4* hv = (const float4*)(h + row0 * FDIM);
#pragma unroll
    for (int i = 0; i < (RB * FDIM / 4) / 256; i++) {
        int f4 = j + i * 256;
        hsv[f4] = (f4 < vf4) ? hv[f4] : make_float4(0.f, 0.f, 0.f, 0.f);
    }
    __syncthreads();

    float acc[8][4];
#pragma unroll
    for (int r = 0; r < 8; r++)
#pragma unroll
        for (int qi = 0; qi < 4; qi++) acc[r][qi] = 0.f;

    for (int kb = 0; kb < FDIM; kb += KC) {
        __syncthreads();
#pragma unroll
        for (int i = 0; i < KC / 4; i++) {
            float4 w4 = *(const float4*)(W + (size_t)j * FDIM + kb + i * 4);
            wt[(i * 4 + 0) * HDIM + j] = w4.x;
            wt[(i * 4 + 1) * HDIM + j] = w4.y;
            wt[(i * 4 + 2) * HDIM + j] = w4.z;
            wt[(i * 4 + 3) * HDIM + j] = w4.w;
        }
        __syncthreads();
#pragma unroll
        for (int k = 0; k < KC; k++) {
            float4 wv = *(const float4*)(wt + k * HDIM + c * 4);
#pragma unroll
            for (int r = 0; r < 8; r++) {
                float hval = hs[(g * 8 + r) * FDIM + kb + k];
                acc[r][0] = fmaf(hval, wv.x, acc[r][0]);
                acc[r][1] = fmaf(hval, wv.y, acc[r][1]);
                acc[r][2] = fmaf(hval, wv.z, acc[r][2]);
                acc[r][3] = fmaf(hval, wv.w, acc[r][3]);
            }
        }
    }
    __syncthreads();
    wt[j] = 0.f;
    wt[256 + j] = 0.f;
    __syncthreads();

    float4 bv = *(const float4*)(bias + c * 4);
    float s0 = 0, s1 = 0, s2 = 0, s3 = 0, q0 = 0, q1 = 0, q2 = 0, q3 = 0;
#pragma unroll
    for (int r = 0; r < 8; r++) {
        int row = g * 8 + r;
        if (row < vrows) {
            float4 v;
            v.x = acc[r][0] + bv.x;
            v.y = acc[r][1] + bv.y;
            v.z = acc[r][2] + bv.z;
            v.w = acc[r][3] + bv.w;
            *(float4*)(h + (row0 + row) * FDIM + c * 4) = v;
            s0 += v.x; s1 += v.y; s2 += v.z; s3 += v.w;
            q0 += v.x * v.x; q1 += v.y * v.y; q2 += v.z * v.z; q3 += v.w * v.w;
        }
    }
    atomicAdd(&wt[c * 4 + 0], s0);
    atomicAdd(&wt[c * 4 + 1], s1);
    atomicAdd(&wt[c * 4 + 2], s2);
    atomicAdd(&wt[c * 4 + 3], s3);
    atomicAdd(&wt[256 + c * 4 + 0], q0);
    atomicAdd(&wt[256 + c * 4 + 1], q1);
    atomicAdd(&wt[256 + c * 4 + 2], q2);
    atomicAdd(&wt[256 + c * 4 + 3], q3);
    __syncthreads();
    atomicAdd(&stat[j], wt[j]);
    atomicAdd(&stat[256 + j], wt[256 + j]);
}
__global__ void k_norm(float* __restrict__ out, const float* __restrict__ ss, int n4) {
    int i = blockIdx.x * blockDim.x + threadIdx.x;
    if (i >= n4) return;
    float4 v = ((float4*)out)[i];
    int c4 = (i & 63) << 2;
    float4 sc = *(const float4*)(ss + c4);
    float4 sh = *(const float4*)(ss + 256 + c4);
    v.x = fmaf(v.x, sc.x, sh.x);
    v.y = fmaf(v.y, sc.y, sh.y);
    v.z = fmaf(v.z, sc.z, sh.z);
    v.w = fmaf(v.w, sc.w, sh.w);
    ((float4*)out)[i] = v;
}

extern "C" void kernel_launch(void* const* d_in, const int* in_sizes, int n_in,
                              void* d_out, int out_size, void* d_ws, size_t ws_size,
                              hipStream_t stream) {
    const float* x   = (const float*)d_in[0];
    const int*   ei  = (const int*)d_in[1];
    const float* W   = (const float*)d_in[2];
    const float* b   = (const float*)d_in[3];
    const float* bnw = (const float*)d_in[4];
    const float* bnb = (const float*)d_in[5];
    float* out = (float*)d_out;
    char* ws = (char*)d_ws;
    const int E = in_sizes[1] / 2;
    const int n4 = NN * FDIM / 4;
    const int n8 = NN * FDIM / 8;
    const int* src = ei;
    const int* dst = ei + E;

    // ---- fast-path ws layout (stat and bcnt adjacent -> one memset) ----
    size_t off = 0;
    float* stat = (float*)(ws + off);          off += 4096;
    int* bcnt   = (int*)(ws + off);            off += 8192;
    unsigned int* pairs = (unsigned int*)(ws + off); off += (size_t)NBKT * CAP * 4;
    off = (off + 255) & ~(size_t)255;
    unsigned short* Wb = (unsigned short*)(ws + off); off += 131072;
    unsigned short* xb = (unsigned short*)(ws + off); off += (size_t)NN * FDIM * 2;
    unsigned short* hb = (unsigned short*)(ws + off); off += (size_t)NN * FDIM * 2;
    const size_t need_fast = off;

    // ---- fallback (fp32 CSR) layout ----
    size_t foff = 0;
    float* fstat  = (float*)(ws + foff); foff += 4096;
    int*   cnt    = (int*)(ws + foff);   foff += 204800;
    int*   offs   = (int*)(ws + foff);   foff += 204800;
    int*   cursor = (int*)(ws + foff);   foff += 204800;
    int*   bsum   = (int*)(ws + foff);   foff += 4096;
    int*   csr    = (int*)(ws + foff);   foff += (size_t)E * 4;
    const size_t need_mid = foff;

    const bool src_fits = (NN <= 65536);   // pair encoding requires 16-bit src
    const int nw4 = HDIM * FDIM / 4;

    if (ws_size >= need_fast && src_fits) {
        hipMemsetAsync(ws, 0, 12288, stream);   // stat (4K) + bcnt (8K)
        int nfb = (E + SBUF2 - 1) / SBUF2;      // worst-case kept <= chunk <= SBUF2
        if (nfb < NFB_MIN) nfb = NFB_MIN;
        const int ncvt = (n4 + nw4 + 255) / 256;
        k_cvtfillA<<<nfb + ncvt, 256, 0, stream>>>((const float4*)x, (const float4*)W,
                                                   (ushort4*)xb, (ushort4*)Wb, n4, nw4,
                                                   src, dst, bcnt, pairs, E, nfb);
        k_mix<<<nfb + NBH, 256, 0, stream>>>((const ushort4*)xb, pairs, bcnt,
                                             src, dst, E, Wb, b, hb, stat, nfb);
        k_aggB<<<NBKT - NBH, 256, 0, stream>>>((const ushort4*)xb, pairs, bcnt,
                                               src, dst, E, Wb, b, hb, stat);
        k_norm8f<<<(n8 + 255) / 256, 256, 0, stream>>>((const ushort8v*)hb, stat,
                                                       bnw, bnb, (float4*)out, n8);
    } else if (ws_size >= need_mid) {
        hipMemsetAsync(fstat, 0, 2 * 256 * sizeof(float), stream);
        hipMemsetAsync(cnt, 0, NN * sizeof(int), stream);
        k_hist<<<(E + 255) / 256, 256, 0, stream>>>(dst, cnt, E);
        k_scan1<<<NBLK_SCAN, 256, 0, stream>>>(cnt, offs, bsum);
        k_scan2<<<1, 64, 0, stream>>>(bsum, NBLK_SCAN);
        k_scan3<<<(NN + 255) / 256, 256, 0, stream>>>(offs, bsum, cursor);
        k_bucket<<<(E + 255) / 256, 256, 0, stream>>>(src, dst, cursor, csr, E);
        k_gather<<<(NN + 3) / 4, 256, 0, stream>>>((const float4*)x, offs, cnt, csr,
                                                   (float4*)out);
        k_gemm_stats<<<(NN + RB - 1) / RB, 256, 0, stream>>>(out, W, b, fstat);
        k_final<<<1, 256, 0, stream>>>(fstat, bnw, bnb, fstat + 512);
        k_norm<<<(n4 + 255) / 256, 256, 0, stream>>>(out, fstat + 512, n4);
    } else {
        hipMemsetAsync(fstat, 0, 2 * 256 * sizeof(float), stream);
        k_copy<<<(n4 + 255) / 256, 256, 0, stream>>>((const float4*)x, (float4*)out, n4);
        long threads = (long)E * 64;
        k_scatter<<<(int)((threads + 255) / 256), 256, 0, stream>>>(x, src, dst, out, E);
        k_gemm_stats<<<(NN + RB - 1) / RB, 256, 0, stream>>>(out, W, b, fstat);
        k_final<<<1, 256, 0, stream>>>(fstat, bnw, bnb, fstat + 512);
        k_norm<<<(n4 + 255) / 256, 256, 0, stream>>>(out, fstat + 512, n4);
    }
}

// Round 13
// 290.173 us; speedup vs baseline: 1.1944x; 1.1944x over previous
//
#include <hip/hip_runtime.h>

#define NN 50000
#define FDIM 256
#define HDIM 256
#define BN_EPS 1e-5f
#define RB 32     // rows per fallback GEMM block
#define KC 16
#define NP 264    // padded LDS row stride (bf16 elems)
#define SCAN_CHUNK 1024
#define NBLK_SCAN ((NN + SCAN_CHUNK - 1) / SCAN_CHUNK)

// partition params
#define BKT 32                 // nodes per bucket == fused GEMM tile rows
#define NBKT 1563              // ceil(NN/32)
#define ECAP 1280              // LDS pair capacity in k_agg_gemm (mean 1024, ~8 sigma)
#define CAP 1280               // fixed slot capacity per bucket (== ECAP)
#define SBUF2 3200             // per-fill-block sorted chunk capacity
#define NFB_MIN 512            // fill blocks (chunk 3125 at E=1.6M) - best measured (r7)
#define FBT 1024               // fill/cvt kernel block size (16 waves)
#define PSC_NPT_F 2            // 2*1024 = 2048 >= NBKT (fill-kernel scan)
// pair encoding: [bkt:11][src:16][ldst:5]
#define PAIR_SRC(p) (((p) >> 5) & 0xFFFFu)
#define PAIR_LDST(p) ((p) & 31u)

typedef __attribute__((ext_vector_type(8))) short short8v;
typedef __attribute__((ext_vector_type(8))) unsigned short ushort8v;
typedef __attribute__((ext_vector_type(4))) float f32x4;

__device__ __forceinline__ float b2f(unsigned short u) {
    return __uint_as_float(((unsigned)u) << 16);
}
__device__ __forceinline__ unsigned short f2b(float f) {  // RNE
    unsigned u = __float_as_uint(f);
    return (unsigned short)((u + 0x7FFFu + ((u >> 16) & 1u)) >> 16);
}

// ====== fused: slot-region fill-sort (blocks 0..nfb-1) + fp32->bf16 convert ======
// Champion config (r7, 291.8us). Fill cost measured FLAT at ~70ns/edge-scanned
// across 7 algorithm families, all geometries, atomic counts, and padding --
// structural floor of edge-regrouping on this chip. Do not re-tune.
__launch_bounds__(FBT)
__global__ void k_cvtfill4(const float4* __restrict__ x, const float4* __restrict__ W,
                           ushort4* __restrict__ xb, ushort4* __restrict__ Wb,
                           int nx4, int nw4,
                           const int* __restrict__ src, const int* __restrict__ dst,
                           int* __restrict__ bcnt, unsigned int* __restrict__ pairs,
                           int E, int nfb) {
    const int bid = blockIdx.x;
    const int t = threadIdx.x;
    if (bid >= nfb) {
        int i = (bid - nfb) * FBT + t;
        if (i < nx4) {
            float4 v = x[i];
            xb[i] = make_ushort4(f2b(v.x), f2b(v.y), f2b(v.z), f2b(v.w));
        } else {
            int j = i - nx4;
            if (j < nw4) {
                float4 v = W[j];
                Wb[j] = make_ushort4(f2b(v.x), f2b(v.y), f2b(v.z), f2b(v.w));
            }
        }
        return;
    }
    // ---- fill-sort portion ----
    __shared__ int lhist[NBKT];         // counts -> cursor -> delta
    __shared__ int lofs[NBKT];          // local exclusive offsets
    __shared__ int ts[FBT];
    __shared__ unsigned int sbuf[SBUF2];
    const int chunk = (E + nfb - 1) / nfb;
    const int c0 = bid * chunk;
    const int c1 = min(E, c0 + chunk);
    const int n = c1 - c0;

    for (int i = t; i < NBKT; i += FBT) lhist[i] = 0;
    __syncthreads();
    for (int e = c0 + t; e < c1; e += FBT) atomicAdd(&lhist[dst[e] >> 5], 1);
    __syncthreads();
    {
        int i0 = t * PSC_NPT_F;
        int s = 0;
        int loc[PSC_NPT_F];
        for (int i = 0; i < PSC_NPT_F; i++) {
            int idx = i0 + i;
            loc[i] = (idx < NBKT) ? lhist[idx] : 0;
            s += loc[i];
        }
        ts[t] = s;
        __syncthreads();
        for (int off = 1; off < FBT; off <<= 1) {
            int val = (t >= off) ? ts[t - off] : 0;
            __syncthreads();
            ts[t] += val;
            __syncthreads();
        }
        int run = ts[t] - s;
        for (int i = 0; i < PSC_NPT_F; i++) {
            int idx = i0 + i;
            if (idx < NBKT) {
                lofs[idx] = run;
                run += loc[i];
            }
        }
    }
    __syncthreads();
    for (int i = t; i < NBKT; i += FBT) lhist[i] = lofs[i];
    __syncthreads();
    // place into sorted LDS buffer
    for (int e = c0 + t; e < c1; e += FBT) {
        int d = dst[e];
        unsigned bkt = (unsigned)d >> 5;
        int rank = atomicAdd(&lhist[bkt], 1);
        sbuf[rank] = (bkt << 21) | ((unsigned)src[e] << 5) | ((unsigned)d & 31u);
    }
    __syncthreads();
    // reserve slot runs; lhist becomes delta = (bkt*CAP + old) - lofs
    for (int i = t; i < NBKT; i += FBT) {
        int cnt = lhist[i] - lofs[i];
        int gb = cnt ? (i * CAP + atomicAdd(&bcnt[i], cnt)) : 0;
        lhist[i] = gb - lofs[i];
    }
    __syncthreads();
    // coalesced write-out, guarded against slot overflow
    for (int j = t; j < n; j += FBT) {
        unsigned int p = sbuf[j];
        unsigned bkt = p >> 21;
        int pos = j + lhist[bkt];
        if (pos < (int)((bkt + 1) * CAP)) pairs[pos] = p;
    }
}

// ===== fused: per 32-node bucket, LDS-sort pairs, VGPR-gather rows into LDS A-tile,
//       then MFMA GEMM (h = A @ Wb^T + b) + BN stats, store bf16 h =====
// (champion config: (256,6), separate ssum/ssq. Gather delivers ~5.6 TB/s = 89%
//  of the 6.3 TB/s measured chip load ceiling -- occupancy-7 variant (r9) and
//  every other perturbation measured slower.)
__launch_bounds__(256, 6)
__global__ void k_agg_gemm(const ushort4* __restrict__ xb4, const unsigned int* __restrict__ pairs,
                           const int* __restrict__ bcnt,
                           const int* __restrict__ srcv, const int* __restrict__ dstv, int E,
                           const unsigned short* __restrict__ Wb, const float* __restrict__ bias,
                           unsigned short* __restrict__ hb, float* __restrict__ stat) {
    __shared__ unsigned int lp[ECAP];
    __shared__ int lhist[BKT];
    __shared__ int lofs[BKT + 1];
    __shared__ unsigned short As[BKT * NP];
    __shared__ float ssum[HDIM];
    __shared__ float ssq[HDIM];
    const int t = threadIdx.x;
    const int lane = t & 63;
    const int wid = t >> 6;
    const int q = lane >> 4;
    const int l16 = lane & 15;
    const int v0 = blockIdx.x * BKT;
    const int ebeg = blockIdx.x * CAP;      // implicit slot base
    const int ecnt = bcnt[blockIdx.x];
    const int vrows = min(BKT, NN - v0);

    ssum[t] = 0.f;
    ssq[t] = 0.f;

    if (ecnt <= ECAP) {
        if (t < BKT) lhist[t] = 0;
        __syncthreads();
        for (int e = t; e < ecnt; e += 256)
            atomicAdd(&lhist[PAIR_LDST(pairs[ebeg + e])], 1);
        __syncthreads();
        if (t == 0) {
            int run = 0;
            for (int r = 0; r < BKT; r++) { lofs[r] = run; run += lhist[r]; }
            lofs[BKT] = run;
        }
        __syncthreads();
        if (t < BKT) lhist[t] = lofs[t];
        __syncthreads();
        for (int e = t; e < ecnt; e += 256) {
            unsigned int p = pairs[ebeg + e];
            int pos = atomicAdd(&lhist[PAIR_LDST(p)], 1);
            lp[pos] = p;
        }
        __syncthreads();
        // gather: wave wid owns rows wid*8 .. wid*8+7
#pragma unroll
        for (int i = 0; i < 8; i++) {
            int r = wid * 8 + i;
            int v = v0 + r;
            if (v < NN) {
                ushort4 u0 = xb4[(size_t)v * 64 + lane];
                float a0 = b2f(u0.x), a1 = b2f(u0.y), a2 = b2f(u0.z), a3 = b2f(u0.w);
                int e0 = __builtin_amdgcn_readfirstlane(lofs[r]);
                int e1 = __builtin_amdgcn_readfirstlane(lofs[r + 1]);
                int e = e0;
                for (; e + 16 <= e1; e += 16) {
                    ushort4 u[16];
#pragma unroll
                    for (int j = 0; j < 16; j++)
                        u[j] = xb4[(size_t)PAIR_SRC(lp[e + j]) * 64 + lane];
#pragma unroll
                    for (int j = 0; j < 16; j++) {
                        a0 += b2f(u[j].x); a1 += b2f(u[j].y);
                        a2 += b2f(u[j].z); a3 += b2f(u[j].w);
                    }
                }
                for (; e + 4 <= e1; e += 4) {
                    ushort4 ua = xb4[(size_t)PAIR_SRC(lp[e]) * 64 + lane];
                    ushort4 ub = xb4[(size_t)PAIR_SRC(lp[e + 1]) * 64 + lane];
                    ushort4 uc = xb4[(size_t)PAIR_SRC(lp[e + 2]) * 64 + lane];
                    ushort4 ud = xb4[(size_t)PAIR_SRC(lp[e + 3]) * 64 + lane];
                    a0 += (b2f(ua.x) + b2f(ub.x)) + (b2f(uc.x) + b2f(ud.x));
                    a1 += (b2f(ua.y) + b2f(ub.y)) + (b2f(uc.y) + b2f(ud.y));
                    a2 += (b2f(ua.z) + b2f(ub.z)) + (b2f(uc.z) + b2f(ud.z));
                    a3 += (b2f(ua.w) + b2f(ub.w)) + (b2f(uc.w) + b2f(ud.w));
                }
                for (; e < e1; e++) {
                    ushort4 ua = xb4[(size_t)PAIR_SRC(lp[e]) * 64 + lane];
                    a0 += b2f(ua.x); a1 += b2f(ua.y); a2 += b2f(ua.z); a3 += b2f(ua.w);
                }
                *(ushort4*)(As + r * NP + lane * 4) =
                    make_ushort4(f2b(a0), f2b(a1), f2b(a2), f2b(a3));
            } else {
                *(ushort4*)(As + r * NP + lane * 4) = make_ushort4(0, 0, 0, 0);
            }
        }
    } else {
        // slot overflow (statistically unreachable): correct raw rescan of edge list
#pragma unroll
        for (int i = 0; i < 8; i++) {
            int r = wid * 8 + i;
            int v = v0 + r;
            float a0 = 0.f, a1 = 0.f, a2 = 0.f, a3 = 0.f;
            if (v < NN) {
                ushort4 u0 = xb4[(size_t)v * 64 + lane];
                a0 = b2f(u0.x); a1 = b2f(u0.y); a2 = b2f(u0.z); a3 = b2f(u0.w);
                for (int e = 0; e < E; e++) {
                    if (dstv[e] == v) {
                        ushort4 cu = xb4[(size_t)srcv[e] * 64 + lane];
                        a0 += b2f(cu.x); a1 += b2f(cu.y); a2 += b2f(cu.z); a3 += b2f(cu.w);
                    }
                }
            }
            *(ushort4*)(As + r * NP + lane * 4) =
                make_ushort4(f2b(a0), f2b(a1), f2b(a2), f2b(a3));
        }
    }
    __syncthreads();

    // ---- MFMA GEMM on the 32xFDIM A-tile ----
    f32x4 acc[2][4];  // [m-tile][n-tile]
#pragma unroll
    for (int mt = 0; mt < 2; mt++)
#pragma unroll
        for (int nt = 0; nt < 4; nt++) acc[mt][nt] = (f32x4)0.f;

    const int w = wid;  // wave -> cols w*64..w*64+63
#pragma unroll
    for (int ks = 0; ks < 8; ks++) {
        const int kk = ks * 32;
        short8v af[2], bf_[4];
#pragma unroll
        for (int mt = 0; mt < 2; mt++)
            af[mt] = *(const short8v*)(As + (mt * 16 + l16) * NP + kk + q * 8);
#pragma unroll
        for (int nt = 0; nt < 4; nt++)
            bf_[nt] = *(const short8v*)(Wb + (size_t)(w * 64 + nt * 16 + l16) * FDIM + kk + q * 8);
#pragma unroll
        for (int mt = 0; mt < 2; mt++)
#pragma unroll
            for (int nt = 0; nt < 4; nt++)
                acc[mt][nt] = __builtin_amdgcn_mfma_f32_16x16x32_bf16(af[mt], bf_[nt], acc[mt][nt], 0, 0, 0);
    }

    // epilogue: bias, bf16 store, BN stats
#pragma unroll
    for (int nt = 0; nt < 4; nt++) {
        const int col = w * 64 + nt * 16 + l16;
        const float bcol = bias[col];
        float s = 0.f, qq = 0.f;
#pragma unroll
        for (int mt = 0; mt < 2; mt++) {
            const int rbase = mt * 16 + q * 4;
#pragma unroll
            for (int r = 0; r < 4; r++) {
                int row = rbase + r;
                if (row < vrows) {
                    float v = acc[mt][nt][r] + bcol;
                    hb[(size_t)(v0 + row) * FDIM + col] = f2b(v);
                    s += v;
                    qq += v * v;
                }
            }
        }
        atomicAdd(&ssum[col], s);
        atomicAdd(&ssq[col], qq);
    }
    __syncthreads();
    atomicAdd(&stat[t], ssum[t]);
    atomicAdd(&stat[256 + t], ssq[t]);
}

// ================= BN finalize folded into normalize =================
__global__ void k_norm8f(const ushort8v* __restrict__ hb8, const float* __restrict__ stat,
                         const float* __restrict__ bn_w, const float* __restrict__ bn_b,
                         float4* __restrict__ out, int n8) {
    __shared__ float ss[512];
    const int t = threadIdx.x;
    {
        const float inv_n = 1.0f / (float)NN;
        float mean = stat[t] * inv_n;
        float var = stat[256 + t] * inv_n - mean * mean;
        float sc = bn_w[t] * rsqrtf(var + BN_EPS);
        ss[t] = sc;
        ss[256 + t] = bn_b[t] - mean * sc;
    }
    __syncthreads();
    int i = blockIdx.x * 256 + t;
    if (i >= n8) return;
    ushort8v u = hb8[i];
    int c8 = (i & 31) << 3;
    float4 sc0 = *(const float4*)(ss + c8);
    float4 sc1 = *(const float4*)(ss + c8 + 4);
    float4 sh0 = *(const float4*)(ss + 256 + c8);
    float4 sh1 = *(const float4*)(ss + 256 + c8 + 4);
    float4 v0, v1;
    v0.x = fmaf(b2f(u[0]), sc0.x, sh0.x);
    v0.y = fmaf(b2f(u[1]), sc0.y, sh0.y);
    v0.z = fmaf(b2f(u[2]), sc0.z, sh0.z);
    v0.w = fmaf(b2f(u[3]), sc0.w, sh0.w);
    v1.x = fmaf(b2f(u[4]), sc1.x, sh1.x);
    v1.y = fmaf(b2f(u[5]), sc1.y, sh1.y);
    v1.z = fmaf(b2f(u[6]), sc1.z, sh1.z);
    v1.w = fmaf(b2f(u[7]), sc1.w, sh1.w);
    out[i * 2 + 0] = v0;
    out[i * 2 + 1] = v1;
}

// ================= fallback fp32 path =================
__global__ void k_final(const float* __restrict__ stat, const float* __restrict__ bn_w,
                        const float* __restrict__ bn_b, float* __restrict__ ss) {
    int j = threadIdx.x;
    const float inv_n = 1.0f / (float)NN;
    float mean = stat[j] * inv_n;
    float var = stat[256 + j] * inv_n - mean * mean;
    float sc = bn_w[j] * rsqrtf(var + BN_EPS);
    ss[j] = sc;
    ss[256 + j] = bn_b[j] - mean * sc;
}
__global__ void k_hist(const int* __restrict__ dst, int* __restrict__ cnt, int E) {
    int e = blockIdx.x * blockDim.x + threadIdx.x;
    if (e < E) atomicAdd(&cnt[dst[e]], 1);
}
__global__ void k_scan1(const int* __restrict__ cnt, int* __restrict__ offs,
                        int* __restrict__ bsum) {
    __shared__ int ts[256];
    int t = threadIdx.x;
    int base = blockIdx.x * SCAN_CHUNK + t * 4;
    int v0 = (base + 0 < NN) ? cnt[base + 0] : 0;
    int v1 = (base + 1 < NN) ? cnt[base + 1] : 0;
    int v2 = (base + 2 < NN) ? cnt[base + 2] : 0;
    int v3 = (base + 3 < NN) ? cnt[base + 3] : 0;
    int tsum = v0 + v1 + v2 + v3;
    ts[t] = tsum;
    __syncthreads();
    for (int off = 1; off < 256; off <<= 1) {
        int val = (t >= off) ? ts[t - off] : 0;
        __syncthreads();
        ts[t] += val;
        __syncthreads();
    }
    int excl = ts[t] - tsum;
    if (t == 255) bsum[blockIdx.x] = ts[255];
    if (base + 0 < NN) offs[base + 0] = excl;
    if (base + 1 < NN) offs[base + 1] = excl + v0;
    if (base + 2 < NN) offs[base + 2] = excl + v0 + v1;
    if (base + 3 < NN) offs[base + 3] = excl + v0 + v1 + v2;
}
__global__ void k_scan2(int* __restrict__ bsum, int nb) {
    __shared__ int s[64];
    int t = threadIdx.x;
    s[t] = (t < nb) ? bsum[t] : 0;
    __syncthreads();
    if (t == 0) {
        int run = 0;
        for (int i = 0; i < nb; i++) { int v = s[i]; s[i] = run; run += v; }
    }
    __syncthreads();
    if (t < nb) bsum[t] = s[t];
}
__global__ void k_scan3(int* __restrict__ offs, const int* __restrict__ bsum,
                        int* __restrict__ cursor) {
    int i = blockIdx.x * blockDim.x + threadIdx.x;
    if (i >= NN) return;
    int o = offs[i] + bsum[i >> 10];
    offs[i] = o;
    cursor[i] = o;
}
__global__ void k_bucket(const int* __restrict__ src, const int* __restrict__ dst,
                         int* __restrict__ cursor, int* __restrict__ csr, int E) {
    int e = blockIdx.x * blockDim.x + threadIdx.x;
    if (e >= E) return;
    int pos = atomicAdd(&cursor[dst[e]], 1);
    csr[pos] = src[e];
}
__global__ void k_copy(const float4* __restrict__ x, float4* __restrict__ out, int n4) {
    int i = blockIdx.x * blockDim.x + threadIdx.x;
    if (i < n4) out[i] = x[i];
}
__global__ void k_scatter(const float* __restrict__ x, const int* __restrict__ src,
                          const int* __restrict__ dst, float* __restrict__ out, int E) {
    int t = blockIdx.x * blockDim.x + threadIdx.x;
    int e = t >> 6;
    if (e >= E) return;
    int c = (t & 63) << 2;
    long s = src[e], d = dst[e];
    const float4 v = *(const float4*)(x + s * FDIM + c);
    float* o = out + d * FDIM + c;
    atomicAdd(o + 0, v.x);
    atomicAdd(o + 1, v.y);
    atomicAdd(o + 2, v.z);
    atomicAdd(o + 3, v.w);
}
__launch_bounds__(256)
__global__ void k_gather(const float4* __restrict__ x, const int* __restrict__ offs,
                         const int* __restrict__ cnt, const int* __restrict__ csr,
                         float4* __restrict__ out) {
    int v = blockIdx.x * 4 + (threadIdx.x >> 6);
    if (v >= NN) return;
    int lane = threadIdx.x & 63;
    int beg = __builtin_amdgcn_readfirstlane(offs[v]);
    int d   = __builtin_amdgcn_readfirstlane(cnt[v]);
    float4 acc = x[(size_t)v * 64 + lane];
    int i = 0;
    for (; i + 4 <= d; i += 4) {
        int s0 = csr[beg + i], s1 = csr[beg + i + 1];
        int s2 = csr[beg + i + 2], s3 = csr[beg + i + 3];
        float4 a = x[(size_t)s0 * 64 + lane];
        float4 b = x[(size_t)s1 * 64 + lane];
        float4 c = x[(size_t)s2 * 64 + lane];
        float4 e = x[(size_t)s3 * 64 + lane];
        acc.x += (a.x + b.x) + (c.x + e.x);
        acc.y += (a.y + b.y) + (c.y + e.y);
        acc.z += (a.z + b.z) + (c.z + e.z);
        acc.w += (a.w + b.w) + (c.w + e.w);
    }
    for (; i < d; i++) {
        int s = csr[beg + i];
        float4 a = x[(size_t)s * 64 + lane];
        acc.x += a.x; acc.y += a.y; acc.z += a.z; acc.w += a.w;
    }
    out[(size_t)v * 64 + lane] = acc;
}
__launch_bounds__(256)
__global__ void k_gemm_stats(float* __restrict__ h,
                             const float* __restrict__ W,
                             const float* __restrict__ bias,
                             float* __restrict__ stat) {
    __shared__ float hs[RB * FDIM];
    __shared__ float wt[KC * HDIM];
    const int j = threadIdx.x;
    const int c = j & 63;
    const int g = j >> 6;
    const long row0 = (long)blockIdx.x * RB;
    const int vrows = min(RB, NN - (int)row0);
    const int vf4 = vrows * (FDIM / 4);

    float4* hsv = (float4*)hs;
    const float4* hv = (const float4*)(h + row0 * FDIM);
#pragma unroll
    for (int i = 0; i < (RB * FDIM / 4) / 256; i++) {
        int f4 = j + i * 256;
        hsv[f4] = (f4 < vf4) ? hv[f4] : make_float4(0.f, 0.f, 0.f, 0.f);
    }
    __syncthreads();

    float acc[8][4];
#pragma unroll
    for (int r = 0; r < 8; r++)
#pragma unroll
        for (int qi = 0; qi < 4; qi++) acc[r][qi] = 0.f;

    for (int kb = 0; kb < FDIM; kb += KC) {
        __syncthreads();
#pragma unroll
        for (int i = 0; i < KC / 4; i++) {
            float4 w4 = *(const float4*)(W + (size_t)j * FDIM + kb + i * 4);
            wt[(i * 4 + 0) * HDIM + j] = w4.x;
            wt[(i * 4 + 1) * HDIM + j] = w4.y;
            wt[(i * 4 + 2) * HDIM + j] = w4.z;
            wt[(i * 4 + 3) * HDIM + j] = w4.w;
        }
        __syncthreads();
#pragma unroll
        for (int k = 0; k < KC; k++) {
            float4 wv = *(const float4*)(wt + k * HDIM + c * 4);
#pragma unroll
            for (int r = 0; r < 8; r++) {
                float hval = hs[(g * 8 + r) * FDIM + kb + k];
                acc[r][0] = fmaf(hval, wv.x, acc[r][0]);
                acc[r][1] = fmaf(hval, wv.y, acc[r][1]);
                acc[r][2] = fmaf(hval, wv.z, acc[r][2]);
                acc[r][3] = fmaf(hval, wv.w, acc[r][3]);
            }
        }
    }
    __syncthreads();
    wt[j] = 0.f;
    wt[256 + j] = 0.f;
    __syncthreads();

    float4 bv = *(const float4*)(bias + c * 4);
    float s0 = 0, s1 = 0, s2 = 0, s3 = 0, q0 = 0, q1 = 0, q2 = 0, q3 = 0;
#pragma unroll
    for (int r = 0; r < 8; r++) {
        int row = g * 8 + r;
        if (row < vrows) {
            float4 v;
            v.x = acc[r][0] + bv.x;
            v.y = acc[r][1] + bv.y;
            v.z = acc[r][2] + bv.z;
            v.w = acc[r][3] + bv.w;
            *(float4*)(h + (row0 + row) * FDIM + c * 4) = v;
            s0 += v.x; s1 += v.y; s2 += v.z; s3 += v.w;
            q0 += v.x * v.x; q1 += v.y * v.y; q2 += v.z * v.z; q3 += v.w * v.w;
        }
    }
    atomicAdd(&wt[c * 4 + 0], s0);
    atomicAdd(&wt[c * 4 + 1], s1);
    atomicAdd(&wt[c * 4 + 2], s2);
    atomicAdd(&wt[c * 4 + 3], s3);
    atomicAdd(&wt[256 + c * 4 + 0], q0);
    atomicAdd(&wt[256 + c * 4 + 1], q1);
    atomicAdd(&wt[256 + c * 4 + 2], q2);
    atomicAdd(&wt[256 + c * 4 + 3], q3);
    __syncthreads();
    atomicAdd(&stat[j], wt[j]);
    atomicAdd(&stat[256 + j], wt[256 + j]);
}
__global__ void k_norm(float* __restrict__ out, const float* __restrict__ ss, int n4) {
    int i = blockIdx.x * blockDim.x + threadIdx.x;
    if (i >= n4) return;
    float4 v = ((float4*)out)[i];
    int c4 = (i & 63) << 2;
    float4 sc = *(const float4*)(ss + c4);
    float4 sh = *(const float4*)(ss + 256 + c4);
    v.x = fmaf(v.x, sc.x, sh.x);
    v.y = fmaf(v.y, sc.y, sh.y);
    v.z = fmaf(v.z, sc.z, sh.z);
    v.w = fmaf(v.w, sc.w, sh.w);
    ((float4*)out)[i] = v;
}

extern "C" void kernel_launch(void* const* d_in, const int* in_sizes, int n_in,
                              void* d_out, int out_size, void* d_ws, size_t ws_size,
                              hipStream_t stream) {
    const float* x   = (const float*)d_in[0];
    const int*   ei  = (const int*)d_in[1];
    const float* W   = (const float*)d_in[2];
    const float* b   = (const float*)d_in[3];
    const float* bnw = (const float*)d_in[4];
    const float* bnb = (const float*)d_in[5];
    float* out = (float*)d_out;
    char* ws = (char*)d_ws;
    const int E = in_sizes[1] / 2;
    const int n4 = NN * FDIM / 4;
    const int n8 = NN * FDIM / 8;
    const int* src = ei;
    const int* dst = ei + E;

    // ---- fast-path ws layout (stat and bcnt adjacent -> one memset) ----
    size_t off = 0;
    float* stat = (float*)(ws + off);          off += 4096;
    int* bcnt   = (int*)(ws + off);            off += 8192;
    unsigned int* pairs = (unsigned int*)(ws + off); off += (size_t)NBKT * CAP * 4;
    off = (off + 255) & ~(size_t)255;
    unsigned short* Wb = (unsigned short*)(ws + off); off += 131072;
    unsigned short* xb = (unsigned short*)(ws + off); off += (size_t)NN * FDIM * 2;
    unsigned short* hb = (unsigned short*)(ws + off); off += (size_t)NN * FDIM * 2;
    const size_t need_fast = off;

    // ---- fallback (fp32 CSR) layout ----
    size_t foff = 0;
    float* fstat  = (float*)(ws + foff); foff += 4096;
    int*   cnt    = (int*)(ws + foff);   foff += 204800;
    int*   offs   = (int*)(ws + foff);   foff += 204800;
    int*   cursor = (int*)(ws + foff);   foff += 204800;
    int*   bsum   = (int*)(ws + foff);   foff += 4096;
    int*   csr    = (int*)(ws + foff);   foff += (size_t)E * 4;
    const size_t need_mid = foff;

    const bool src_fits = (NN <= 65536);   // pair encoding requires 16-bit src
    const int nw4 = HDIM * FDIM / 4;

    if (ws_size >= need_fast && src_fits) {
        hipMemsetAsync(ws, 0, 12288, stream);   // stat (4K) + bcnt (8K)
        int nfb = (E + SBUF2 - 1) / SBUF2;      // guarantee chunk <= SBUF2
        if (nfb < NFB_MIN) nfb = NFB_MIN;
        const int ncvt = (n4 + nw4 + FBT - 1) / FBT;
        k_cvtfill4<<<nfb + ncvt, FBT, 0, stream>>>((const float4*)x, (const float4*)W,
                                                   (ushort4*)xb, (ushort4*)Wb, n4, nw4,
                                                   src, dst, bcnt, pairs, E, nfb);
        k_agg_gemm<<<NBKT, 256, 0, stream>>>((const ushort4*)xb, pairs, bcnt,
                                             src, dst, E, Wb, b, hb, stat);
        k_norm8f<<<(n8 + 255) / 256, 256, 0, stream>>>((const ushort8v*)hb, stat,
                                                       bnw, bnb, (float4*)out, n8);
    } else if (ws_size >= need_mid) {
        hipMemsetAsync(fstat, 0, 2 * 256 * sizeof(float), stream);
        hipMemsetAsync(cnt, 0, NN * sizeof(int), stream);
        k_hist<<<(E + 255) / 256, 256, 0, stream>>>(dst, cnt, E);
        k_scan1<<<NBLK_SCAN, 256, 0, stream>>>(cnt, offs, bsum);
        k_scan2<<<1, 64, 0, stream>>>(bsum, NBLK_SCAN);
        k_scan3<<<(NN + 255) / 256, 256, 0, stream>>>(offs, bsum, cursor);
        k_bucket<<<(E + 255) / 256, 256, 0, stream>>>(src, dst, cursor, csr, E);
        k_gather<<<(NN + 3) / 4, 256, 0, stream>>>((const float4*)x, offs, cnt, csr,
                                                   (float4*)out);
        k_gemm_stats<<<(NN + RB - 1) / RB, 256, 0, stream>>>(out, W, b, fstat);
        k_final<<<1, 256, 0, stream>>>(fstat, bnw, bnb, fstat + 512);
        k_norm<<<(n4 + 255) / 256, 256, 0, stream>>>(out, fstat + 512, n4);
    } else {
        hipMemsetAsync(fstat, 0, 2 * 256 * sizeof(float), stream);
        k_copy<<<(n4 + 255) / 256, 256, 0, stream>>>((const float4*)x, (float4*)out, n4);
        long threads = (long)E * 64;
        k_scatter<<<(int)((threads + 255) / 256), 256, 0, stream>>>(x, src, dst, out, E);
        k_gemm_stats<<<(NN + RB - 1) / RB, 256, 0, stream>>>(out, W, b, fstat);
        k_final<<<1, 256, 0, stream>>>(fstat, bnw, bnb, fstat + 512);
        k_norm<<<(n4 + 255) / 256, 256, 0, stream>>>(out, fstat + 512, n4);
    }
}